// Round 11
// baseline (251.879 us; speedup 1.0000x reference)
//
#include <hip/hip_runtime.h>

#define CIN 256
#define COUT 256
#define Hh 64
#define Ww 64
#define Bb 4
#define HW 4096
#define NKK 9

typedef __attribute__((ext_vector_type(8))) short bf16x8;
typedef __attribute__((ext_vector_type(4))) float f32x4;

__device__ __forceinline__ unsigned short f2bf(float f) {
  unsigned int u = __builtin_bit_cast(unsigned int, f);
  unsigned int r = u + 0x7FFFu + ((u >> 16) & 1u);
  return (unsigned short)(r >> 16);
}
__device__ __forceinline__ float bf2f(unsigned short h) {
  unsigned int u = ((unsigned int)h) << 16;
  return __builtin_bit_cast(float, u);
}
// ISA-level loads: asm volatile => compiler cannot re-sink them (r7/r8/r10
// all failed at C level). Data valid only after explicit s_waitcnt.
__device__ __forceinline__ bf16x8 gldx4(const void* p) {
  bf16x8 r;
  asm volatile("global_load_dwordx4 %0, %1, off" : "=&v"(r) : "v"(p));
  return r;
}
__device__ __forceinline__ float gld1(const void* p) {
  float r;
  asm volatile("global_load_dword %0, %1, off" : "=&v"(r) : "v"(p));
  return r;
}

#define WB_ELEMS 589824    // 9*4*16*2*64*8  (main weights, fragment order)
#define WOB_ELEMS 147456   // 9*4*2*2*64*8   (offset-conv weights, oc padded to 32)
#define OFFPART_FLOATS (Bb * 18 * HW)

// ---------------------------------------------------------------------------
// Prep: pack weights into exact MFMA B-fragment order (bf16).
// ---------------------------------------------------------------------------
__global__ __launch_bounds__(256) void prep_weights_kernel(
    const float* __restrict__ w, const float* __restrict__ ow,
    unsigned short* __restrict__ wBh, unsigned short* __restrict__ wBl,
    unsigned short* __restrict__ wOBh) {
  int i = blockIdx.x * 256 + threadIdx.x;
  if (i < WB_ELEMS) {
    int e = i & 7;
    int lane = (i >> 3) & 63;
    int ks = (i >> 9) & 1;
    int nt = (i >> 10) & 15;
    int cb = (i >> 14) & 3;
    int kk = i >> 16;
    int c = cb * 64 + ks * 32 + (lane >> 4) * 8 + e;
    int oc = nt * 16 + (lane & 15);
    float v = w[((size_t)oc * CIN + c) * 9 + kk];
    unsigned short hi = f2bf(v);
    wBh[i] = hi;
    wBl[i] = f2bf(v - bf2f(hi));
  } else {
    int j = i - WB_ELEMS;
    if (j < WOB_ELEMS) {
      int e = j & 7;
      int lane = (j >> 3) & 63;
      int ks = (j >> 9) & 1;
      int nt = (j >> 10) & 1;
      int cb = (j >> 11) & 3;
      int kk = j >> 13;
      int c = cb * 64 + ks * 32 + (lane >> 4) * 8 + e;
      int oc = nt * 16 + (lane & 15);
      float v = (oc < 18) ? ow[((size_t)oc * CIN + c) * 9 + kk] : 0.0f;
      wOBh[j] = f2bf(v);
    }
  }
}

// ---------------------------------------------------------------------------
// Offset conv via MFMA, channel-split (2 blocks/CU). UNCHANGED this round
// (attribution discipline) — next round gets the same asm-batch treatment.
// ---------------------------------------------------------------------------
__global__ __launch_bounds__(256) void offset_conv_kernel(
    const float* __restrict__ x,
    const unsigned short* __restrict__ wOBh,
    const float* __restrict__ ob,
    float* __restrict__ op0, float* __restrict__ op1) {
  __shared__ __align__(16) unsigned short smA[64 * 64];

  const int tid = threadIdx.x;
  const int bid = blockIdx.x;
  const int logical = (bid & 7) * 64 + (bid >> 3);  // T1
  const int chalf = logical & 1;
  const int rowid = logical >> 1;
  const int ho = rowid & 63;
  const int b  = rowid >> 6;
  const int lane = tid & 63;
  const int wv = tid >> 6;
  const int px = tid & 63;
  const int c8g = tid >> 6;

  f32x4 acc[2];
  #pragma unroll
  for (int n = 0; n < 2; ++n)
    #pragma unroll
    for (int q = 0; q < 4; ++q) acc[n][q] = 0.0f;

  const float* xb = x + (size_t)b * CIN * HW;

  for (int kk = 0; kk < NKK; ++kk) {
    int ky = kk / 3, kx = kk % 3;
    int y = ho - 1 + ky;
    if (y < 0 || y >= Hh) continue;
    int xx = px - 1 + kx;
    bool xv = (xx >= 0 && xx < Ww);
    int xxc = min(max(xx, 0), Ww - 1);
    const float* xrow = xb + (size_t)y * Ww + xxc;
    #pragma unroll
    for (int cb2 = 0; cb2 < 2; ++cb2) {
      int cb = chalf * 2 + cb2;
      __syncthreads();
      #pragma unroll
      for (int pass = 0; pass < 2; ++pass) {
        int c8 = c8g * 2 + pass;
        int cbase = cb * 64 + c8 * 8;
        unsigned int ph[4];
        #pragma unroll
        for (int j = 0; j < 4; ++j) {
          float v0 = xv ? xrow[(size_t)(cbase + 2 * j) * HW] : 0.0f;
          float v1 = xv ? xrow[(size_t)(cbase + 2 * j + 1) * HW] : 0.0f;
          ph[j] = (unsigned int)f2bf(v0) | ((unsigned int)f2bf(v1) << 16);
        }
        int boff = px * 128 + ((c8 ^ (px & 7)) * 16);
        *(uint4*)((char*)smA + boff) = make_uint4(ph[0], ph[1], ph[2], ph[3]);
      }
      __syncthreads();
      bf16x8 a[2];
      #pragma unroll
      for (int ks = 0; ks < 2; ++ks) {
        int pxa = wv * 16 + (lane & 15);
        int cg = ks * 4 + (lane >> 4);
        a[ks] = *(const bf16x8*)((const char*)smA + pxa * 128 + ((cg ^ (pxa & 7)) * 16));
      }
      bf16x8 wb[2][2];
      #pragma unroll
      for (int nt = 0; nt < 2; ++nt)
        #pragma unroll
        for (int ks = 0; ks < 2; ++ks) {
          size_t wi = ((((size_t)(kk * 4 + cb) * 2 + nt) * 2 + ks) * 64 + lane) * 8;
          wb[nt][ks] = *(const bf16x8*)(wOBh + wi);
        }
      #pragma unroll
      for (int nt = 0; nt < 2; ++nt)
        #pragma unroll
        for (int ks = 0; ks < 2; ++ks)
          acc[nt] = __builtin_amdgcn_mfma_f32_16x16x32_bf16(a[ks], wb[nt][ks], acc[nt], 0, 0, 0);
    }
  }
  float* opart = chalf ? op1 : op0;
  #pragma unroll
  for (int nt = 0; nt < 2; ++nt) {
    int oc = nt * 16 + (lane & 15);
    if (oc < 18) {
      float bias = chalf ? 0.0f : ob[oc];
      float4 v4 = make_float4(acc[nt][0] + bias, acc[nt][1] + bias,
                              acc[nt][2] + bias, acc[nt][3] + bias);
      int pxo = wv * 16 + (lane >> 4) * 4;
      *(float4*)(opart + ((size_t)b * 18 + oc) * HW + (size_t)ho * Ww + pxo) = v4;
    }
  }
}

// ---------------------------------------------------------------------------
// Main: r5 structure (64 px x 256 oc, grid 256, 8 waves) with ISA-level
// load batching per chunk (T4 / AITER pattern):
//   [ds_read A] [asm: 16 weight dwordx4] [asm: 32 gather dword (ch+1)]
//   [s_waitcnt vmcnt(32) = weights only; sched_barrier] [48 MFMAs]
//   [s_waitcnt vmcnt(0) = gathers; sched_barrier] [staging math + ds_write]
//   [barrier]
// Gathers are in flight across the whole MFMA phase; weights wait once.
// ---------------------------------------------------------------------------
__global__ __launch_bounds__(512, 2) void deform_main_kernel(
    const float* __restrict__ x,
    const float* __restrict__ op0, const float* __restrict__ op1,
    const unsigned short* __restrict__ wBh, const unsigned short* __restrict__ wBl,
    float* __restrict__ out) {
  __shared__ __align__(16) int4   sm_idx[NKK][64];   // 4 clamped gather indices
  __shared__ __align__(16) float4 sm_w[NKK][64];     // mask-folded bilinear weights
  __shared__ __align__(16) unsigned short smAh[2][64 * 64];
  __shared__ __align__(16) unsigned short smAl[2][64 * 64];

  const int tid = threadIdx.x;
  const int bid = blockIdx.x;
  const int blk = (bid & 7) * 32 + (bid >> 3);  // T1: 32 logical rows / XCD
  const int ho = blk & 63;
  const int b  = blk >> 6;
  const int lane = tid & 63;
  const int wv = tid >> 6;
  const int mh = wv >> 2;       // px half (32 px)
  const int og = wv & 3;        // oc group (64 oc)

  // ---- Phase 0: bilinear meta for 9 x 64 (kk, px); offset = op0 + op1 ----
  const float* ob0 = op0 + (size_t)b * 18 * HW + (size_t)ho * Ww;
  const float* ob1 = op1 + (size_t)b * 18 * HW + (size_t)ho * Ww;
  for (int i = tid; i < NKK * 64; i += 512) {
    int pp = i & 63;
    int kk = i >> 6;
    int ky = kk / 3, kx = kk % 3;
    float dy = ob0[(size_t)(2 * kk) * HW + pp] + ob1[(size_t)(2 * kk) * HW + pp];
    float dx = ob0[(size_t)(2 * kk + 1) * HW + pp] + ob1[(size_t)(2 * kk + 1) * HW + pp];
    float py = (float)(ho - 1 + ky) + dy;
    float pxf = (float)(pp - 1 + kx) + dx;
    float y0f = floorf(py), x0f = floorf(pxf);
    int y0 = (int)y0f, x0 = (int)x0f;
    float wy1 = py - y0f, wy0 = 1.0f - wy1;
    float wx1 = pxf - x0f, wx0 = 1.0f - wx1;
    int4 idx4; float4 w4;
    { bool v = (y0 >= 0 && y0 < Hh && x0 >= 0 && x0 < Ww);
      idx4.x = min(max(y0, 0), Hh - 1) * Ww + min(max(x0, 0), Ww - 1);
      w4.x = v ? wy0 * wx0 : 0.0f; }
    { int xs = x0 + 1; bool v = (y0 >= 0 && y0 < Hh && xs >= 0 && xs < Ww);
      idx4.y = min(max(y0, 0), Hh - 1) * Ww + min(max(xs, 0), Ww - 1);
      w4.y = v ? wy0 * wx1 : 0.0f; }
    { int ys = y0 + 1; bool v = (ys >= 0 && ys < Hh && x0 >= 0 && x0 < Ww);
      idx4.z = min(max(ys, 0), Hh - 1) * Ww + min(max(x0, 0), Ww - 1);
      w4.z = v ? wy1 * wx0 : 0.0f; }
    { int ys = y0 + 1, xs = x0 + 1; bool v = (ys >= 0 && ys < Hh && xs >= 0 && xs < Ww);
      idx4.w = min(max(ys, 0), Hh - 1) * Ww + min(max(xs, 0), Ww - 1);
      w4.w = v ? wy1 * wx1 : 0.0f; }
    sm_idx[kk][pp] = idx4;
    sm_w[kk][pp] = w4;
  }
  __syncthreads();

  f32x4 acc[2][4];
  #pragma unroll
  for (int m = 0; m < 2; ++m)
    #pragma unroll
    for (int n = 0; n < 4; ++n)
      #pragma unroll
      for (int q = 0; q < 4; ++q) acc[m][n][q] = 0.0f;

  const float* xb = x + (size_t)b * CIN * HW;
  const int spx = tid & 63;   // stage pixel
  const int sc8 = tid >> 6;   // stage 8-channel group (0..7)
  const int sboff = spx * 128 + ((sc8 ^ (spx & 7)) * 16);

  // ---- prologue: stage chunk 0 (kk=0, cb=0), plain C loads ----
  {
    int4 ip = sm_idx[0][spx];
    float4 wp = sm_w[0][spx];
    const float* xpB = xb + (size_t)(sc8 * 8) * HW;
    unsigned int ph[4], pl[4];
    #pragma unroll
    for (int j2 = 0; j2 < 4; ++j2) {
      const float* xp0 = xpB + (size_t)(2 * j2) * HW;
      const float* xp1 = xpB + (size_t)(2 * j2 + 1) * HW;
      float v0 = xp0[ip.x] * wp.x + xp0[ip.y] * wp.y + xp0[ip.z] * wp.z + xp0[ip.w] * wp.w;
      float v1 = xp1[ip.x] * wp.x + xp1[ip.y] * wp.y + xp1[ip.z] * wp.z + xp1[ip.w] * wp.w;
      unsigned short h0 = f2bf(v0), h1 = f2bf(v1);
      ph[j2] = (unsigned int)h0 | ((unsigned int)h1 << 16);
      pl[j2] = (unsigned int)f2bf(v0 - bf2f(h0)) | ((unsigned int)f2bf(v1 - bf2f(h1)) << 16);
    }
    *(uint4*)((char*)smAh[0] + sboff) = make_uint4(ph[0], ph[1], ph[2], ph[3]);
    *(uint4*)((char*)smAl[0] + sboff) = make_uint4(pl[0], pl[1], pl[2], pl[3]);
  }
  __syncthreads();

  for (int ch = 0; ch < 36; ++ch) {
    const int cur = ch & 1;
    const int kk = ch >> 2, cb = ch & 3;
    const bool have_next = (ch + 1 < 36);

    // ---- 1. ds_read A-frags for chunk ch (lgkm counter) ----
    bf16x8 ah[2][2], al[2][2];
    #pragma unroll
    for (int m = 0; m < 2; ++m)
      #pragma unroll
      for (int ks = 0; ks < 2; ++ks) {
        int pxa = mh * 32 + m * 16 + (lane & 15);
        int cg = ks * 4 + (lane >> 4);
        int aoff = pxa * 128 + ((cg ^ (pxa & 7)) * 16);
        ah[m][ks] = *(const bf16x8*)((const char*)smAh[cur] + aoff);
        al[m][ks] = *(const bf16x8*)((const char*)smAl[cur] + aoff);
      }

    // ---- 2. asm: 16 weight dwordx4 loads (oldest in vmcnt) ----
    bf16x8 wh[4][2], wl[4][2];
    #pragma unroll
    for (int nt = 0; nt < 4; ++nt)
      #pragma unroll
      for (int ks = 0; ks < 2; ++ks) {
        size_t wi = ((((size_t)(kk * 4 + cb) * 16 + (og * 4 + nt)) * 2 + ks) * 64 + lane) * 8;
        wh[nt][ks] = gldx4(wBh + wi);
        wl[nt][ks] = gldx4(wBl + wi);
      }

    // ---- 3. asm: 32 gather dword loads for chunk ch+1 (young in vmcnt) ----
    float g[8][4];
    int4 ipn; float4 wpn;
    if (have_next) {
      int kkn = (ch + 1) >> 2, cbn = (ch + 1) & 3;
      ipn = sm_idx[kkn][spx];
      wpn = sm_w[kkn][spx];
      const float* xpB = xb + (size_t)(cbn * 64 + sc8 * 8) * HW;
      #pragma unroll
      for (int j = 0; j < 8; ++j) {
        const float* xp = xpB + (size_t)j * HW;
        g[j][0] = gld1(xp + ipn.x);
        g[j][1] = gld1(xp + ipn.y);
        g[j][2] = gld1(xp + ipn.z);
        g[j][3] = gld1(xp + ipn.w);
      }
    }

    // ---- 4. wait for weights only (32 gathers stay in flight) ----
    if (have_next) { asm volatile("s_waitcnt vmcnt(32)" ::: "memory"); }
    else           { asm volatile("s_waitcnt vmcnt(0)"  ::: "memory"); }
    __builtin_amdgcn_sched_barrier(0);

    // ---- 5. 48 MFMAs (compiler inserts lgkmcnt for A-frags) ----
    #pragma unroll
    for (int nt = 0; nt < 4; ++nt)
      #pragma unroll
      for (int ks = 0; ks < 2; ++ks) {
        acc[0][nt] = __builtin_amdgcn_mfma_f32_16x16x32_bf16(ah[0][ks], wh[nt][ks], acc[0][nt], 0, 0, 0);
        acc[1][nt] = __builtin_amdgcn_mfma_f32_16x16x32_bf16(ah[1][ks], wh[nt][ks], acc[1][nt], 0, 0, 0);
        acc[0][nt] = __builtin_amdgcn_mfma_f32_16x16x32_bf16(al[0][ks], wh[nt][ks], acc[0][nt], 0, 0, 0);
        acc[1][nt] = __builtin_amdgcn_mfma_f32_16x16x32_bf16(al[1][ks], wh[nt][ks], acc[1][nt], 0, 0, 0);
        acc[0][nt] = __builtin_amdgcn_mfma_f32_16x16x32_bf16(ah[0][ks], wl[nt][ks], acc[0][nt], 0, 0, 0);
        acc[1][nt] = __builtin_amdgcn_mfma_f32_16x16x32_bf16(ah[1][ks], wl[nt][ks], acc[1][nt], 0, 0, 0);
      }

    // ---- 6./7. drain gathers, staging math, ds_write ----
    if (have_next) {
      asm volatile("s_waitcnt vmcnt(0)" ::: "memory");
      __builtin_amdgcn_sched_barrier(0);
      unsigned int ph[4], pl[4];
      #pragma unroll
      for (int j2 = 0; j2 < 4; ++j2) {
        float v0 = g[2 * j2][0] * wpn.x + g[2 * j2][1] * wpn.y +
                   g[2 * j2][2] * wpn.z + g[2 * j2][3] * wpn.w;
        float v1 = g[2 * j2 + 1][0] * wpn.x + g[2 * j2 + 1][1] * wpn.y +
                   g[2 * j2 + 1][2] * wpn.z + g[2 * j2 + 1][3] * wpn.w;
        unsigned short h0 = f2bf(v0), h1 = f2bf(v1);
        ph[j2] = (unsigned int)h0 | ((unsigned int)h1 << 16);
        pl[j2] = (unsigned int)f2bf(v0 - bf2f(h0)) | ((unsigned int)f2bf(v1 - bf2f(h1)) << 16);
      }
      *(uint4*)((char*)smAh[cur ^ 1] + sboff) = make_uint4(ph[0], ph[1], ph[2], ph[3]);
      *(uint4*)((char*)smAl[cur ^ 1] + sboff) = make_uint4(pl[0], pl[1], pl[2], pl[3]);
    }
    __syncthreads();
  }

  // ---- epilogue: px = mh*32 + m*16 + (lane>>4)*4 + r ----
  #pragma unroll
  for (int m = 0; m < 2; ++m) {
    #pragma unroll
    for (int nt = 0; nt < 4; ++nt) {
      int oc = og * 64 + nt * 16 + (lane & 15);
      int pxo = mh * 32 + m * 16 + (lane >> 4) * 4;
      float4 v4 = make_float4(acc[m][nt][0], acc[m][nt][1], acc[m][nt][2], acc[m][nt][3]);
      *(float4*)(out + ((size_t)b * COUT + oc) * HW + (size_t)ho * Ww + pxo) = v4;
    }
  }
}

// ---------------------------------------------------------------------------
extern "C" void kernel_launch(void* const* d_in, const int* in_sizes, int n_in,
                              void* d_out, int out_size, void* d_ws, size_t ws_size,
                              hipStream_t stream) {
  const float* x  = (const float*)d_in[0];
  const float* ow = (const float*)d_in[1];
  const float* ob = (const float*)d_in[2];
  const float* w  = (const float*)d_in[3];
  float* out = (float*)d_out;

  float* op0 = (float*)d_ws;
  float* op1 = op0 + OFFPART_FLOATS;
  unsigned short* wBh  = (unsigned short*)(op1 + OFFPART_FLOATS);
  unsigned short* wBl  = wBh + WB_ELEMS;
  unsigned short* wOBh = wBl + WB_ELEMS;

  hipLaunchKernelGGL(prep_weights_kernel, dim3((WB_ELEMS + WOB_ELEMS) / 256),
                     dim3(256), 0, stream, w, ow, wBh, wBl, wOBh);
  hipLaunchKernelGGL(offset_conv_kernel, dim3(Bb * Hh * 2), dim3(256),
                     0, stream, x, wOBh, ob, op0, op1);
  hipLaunchKernelGGL(deform_main_kernel, dim3(Bb * Hh), dim3(512),
                     0, stream, x, op0, op1, wBh, wBl, out);
}

// Round 12
// 210.534 us; speedup vs baseline: 1.1964x; 1.1964x over previous
//
#include <hip/hip_runtime.h>

#define CIN 256
#define COUT 256
#define Hh 64
#define Ww 64
#define Bb 4
#define HW 4096
#define NKK 9

typedef __attribute__((ext_vector_type(8))) short bf16x8;
typedef __attribute__((ext_vector_type(4))) float f32x4;

__device__ __forceinline__ unsigned short f2bf(float f) {
  unsigned int u = __builtin_bit_cast(unsigned int, f);
  unsigned int r = u + 0x7FFFu + ((u >> 16) & 1u);
  return (unsigned short)(r >> 16);
}
__device__ __forceinline__ float bf2f(unsigned short h) {
  unsigned int u = ((unsigned int)h) << 16;
  return __builtin_bit_cast(float, u);
}
// ISA-level loads (compiler cannot re-sink; data valid after s_waitcnt).
__device__ __forceinline__ bf16x8 gldx4(const void* p) {
  bf16x8 r;
  asm volatile("global_load_dwordx4 %0, %1, off" : "=&v"(r) : "v"(p));
  return r;
}
__device__ __forceinline__ float2 gldx2(const void* p) {
  float2 r;
  asm volatile("global_load_dwordx2 %0, %1, off" : "=&v"(r) : "v"(p));
  return r;
}
// bilinear from two row-pair loads + eq-select (border folded into w)
__device__ __forceinline__ float bil(float2 f0, float2 f1, int eq, float4 w) {
  float t00 = eq ? f0.x : f0.y;
  float t01 = eq ? f0.y : f0.x;
  float t10 = eq ? f1.x : f1.y;
  float t11 = eq ? f1.y : f1.x;
  return t00 * w.x + t01 * w.y + t10 * w.z + t11 * w.w;
}

#define WB_ELEMS 589824    // 9*4*16*2*64*8  (main weights, fragment order)
#define WOB_ELEMS 147456   // 9*4*2*2*64*8   (offset-conv weights, oc padded to 32)
#define OFFPART_FLOATS (Bb * 18 * HW)

// ---------------------------------------------------------------------------
// Prep: pack weights into exact MFMA B-fragment order (bf16). UNCHANGED.
// ---------------------------------------------------------------------------
__global__ __launch_bounds__(256) void prep_weights_kernel(
    const float* __restrict__ w, const float* __restrict__ ow,
    unsigned short* __restrict__ wBh, unsigned short* __restrict__ wBl,
    unsigned short* __restrict__ wOBh) {
  int i = blockIdx.x * 256 + threadIdx.x;
  if (i < WB_ELEMS) {
    int e = i & 7;
    int lane = (i >> 3) & 63;
    int ks = (i >> 9) & 1;
    int nt = (i >> 10) & 15;
    int cb = (i >> 14) & 3;
    int kk = i >> 16;
    int c = cb * 64 + ks * 32 + (lane >> 4) * 8 + e;
    int oc = nt * 16 + (lane & 15);
    float v = w[((size_t)oc * CIN + c) * 9 + kk];
    unsigned short hi = f2bf(v);
    wBh[i] = hi;
    wBl[i] = f2bf(v - bf2f(hi));
  } else {
    int j = i - WB_ELEMS;
    if (j < WOB_ELEMS) {
      int e = j & 7;
      int lane = (j >> 3) & 63;
      int ks = (j >> 9) & 1;
      int nt = (j >> 10) & 1;
      int cb = (j >> 11) & 3;
      int kk = j >> 13;
      int c = cb * 64 + ks * 32 + (lane >> 4) * 8 + e;
      int oc = nt * 16 + (lane & 15);
      float v = (oc < 18) ? ow[((size_t)oc * CIN + c) * 9 + kk] : 0.0f;
      wOBh[j] = f2bf(v);
    }
  }
}

// ---------------------------------------------------------------------------
// Offset conv via MFMA, channel-split (2 blocks/CU). UNCHANGED (attribution).
// ---------------------------------------------------------------------------
__global__ __launch_bounds__(256) void offset_conv_kernel(
    const float* __restrict__ x,
    const unsigned short* __restrict__ wOBh,
    const float* __restrict__ ob,
    float* __restrict__ op0, float* __restrict__ op1) {
  __shared__ __align__(16) unsigned short smA[64 * 64];

  const int tid = threadIdx.x;
  const int bid = blockIdx.x;
  const int logical = (bid & 7) * 64 + (bid >> 3);  // T1
  const int chalf = logical & 1;
  const int rowid = logical >> 1;
  const int ho = rowid & 63;
  const int b  = rowid >> 6;
  const int lane = tid & 63;
  const int wv = tid >> 6;
  const int px = tid & 63;
  const int c8g = tid >> 6;

  f32x4 acc[2];
  #pragma unroll
  for (int n = 0; n < 2; ++n)
    #pragma unroll
    for (int q = 0; q < 4; ++q) acc[n][q] = 0.0f;

  const float* xb = x + (size_t)b * CIN * HW;

  for (int kk = 0; kk < NKK; ++kk) {
    int ky = kk / 3, kx = kk % 3;
    int y = ho - 1 + ky;
    if (y < 0 || y >= Hh) continue;
    int xx = px - 1 + kx;
    bool xv = (xx >= 0 && xx < Ww);
    int xxc = min(max(xx, 0), Ww - 1);
    const float* xrow = xb + (size_t)y * Ww + xxc;
    #pragma unroll
    for (int cb2 = 0; cb2 < 2; ++cb2) {
      int cb = chalf * 2 + cb2;
      __syncthreads();
      #pragma unroll
      for (int pass = 0; pass < 2; ++pass) {
        int c8 = c8g * 2 + pass;
        int cbase = cb * 64 + c8 * 8;
        unsigned int ph[4];
        #pragma unroll
        for (int j = 0; j < 4; ++j) {
          float v0 = xv ? xrow[(size_t)(cbase + 2 * j) * HW] : 0.0f;
          float v1 = xv ? xrow[(size_t)(cbase + 2 * j + 1) * HW] : 0.0f;
          ph[j] = (unsigned int)f2bf(v0) | ((unsigned int)f2bf(v1) << 16);
        }
        int boff = px * 128 + ((c8 ^ (px & 7)) * 16);
        *(uint4*)((char*)smA + boff) = make_uint4(ph[0], ph[1], ph[2], ph[3]);
      }
      __syncthreads();
      bf16x8 a[2];
      #pragma unroll
      for (int ks = 0; ks < 2; ++ks) {
        int pxa = wv * 16 + (lane & 15);
        int cg = ks * 4 + (lane >> 4);
        a[ks] = *(const bf16x8*)((const char*)smA + pxa * 128 + ((cg ^ (pxa & 7)) * 16));
      }
      bf16x8 wb[2][2];
      #pragma unroll
      for (int nt = 0; nt < 2; ++nt)
        #pragma unroll
        for (int ks = 0; ks < 2; ++ks) {
          size_t wi = ((((size_t)(kk * 4 + cb) * 2 + nt) * 2 + ks) * 64 + lane) * 8;
          wb[nt][ks] = *(const bf16x8*)(wOBh + wi);
        }
      #pragma unroll
      for (int nt = 0; nt < 2; ++nt)
        #pragma unroll
        for (int ks = 0; ks < 2; ++ks)
          acc[nt] = __builtin_amdgcn_mfma_f32_16x16x32_bf16(a[ks], wb[nt][ks], acc[nt], 0, 0, 0);
    }
  }
  float* opart = chalf ? op1 : op0;
  #pragma unroll
  for (int nt = 0; nt < 2; ++nt) {
    int oc = nt * 16 + (lane & 15);
    if (oc < 18) {
      float bias = chalf ? 0.0f : ob[oc];
      float4 v4 = make_float4(acc[nt][0] + bias, acc[nt][1] + bias,
                              acc[nt][2] + bias, acc[nt][3] + bias);
      int pxo = wv * 16 + (lane >> 4) * 4;
      *(float4*)(opart + ((size_t)b * 18 + oc) * HW + (size_t)ho * Ww + pxo) = v4;
    }
  }
}

// ---------------------------------------------------------------------------
// Main v12: VMEM-instruction reduction.
//  - 8 waves each own a UNIQUE 32-oc group over all 64 px (weight dedup:
//    64 weight dwordx4 / chunk / CU instead of 128).
//  - gathers as row-pair global_load_dwordx2 via r9 meta (eq-select,
//    borders folded into weights): 128 gather instrs / chunk / CU vs 256.
//  - r11 asm-batch schedule kept: weights oldest, vmcnt(16) before MFMAs,
//    gathers drain at vmcnt(0) after MFMAs.
// ---------------------------------------------------------------------------
__global__ __launch_bounds__(512, 2) void deform_main_kernel(
    const float* __restrict__ x,
    const float* __restrict__ op0, const float* __restrict__ op1,
    const unsigned short* __restrict__ wBh, const unsigned short* __restrict__ wBl,
    float* __restrict__ out) {
  __shared__ __align__(16) int4   sm_m[NKK][64];   // {off0, off1, eq, 0}
  __shared__ __align__(16) float4 sm_w[NKK][64];   // border-folded bilinear w
  __shared__ __align__(16) unsigned short smAh[2][64 * 64];
  __shared__ __align__(16) unsigned short smAl[2][64 * 64];

  const int tid = threadIdx.x;
  const int bid = blockIdx.x;
  const int blk = (bid & 7) * 32 + (bid >> 3);  // T1: 32 logical rows / XCD
  const int ho = blk & 63;
  const int b  = blk >> 6;
  const int lane = tid & 63;
  const int wvu = __builtin_amdgcn_readfirstlane(tid >> 6);  // oc-group 0..7

  // ---- Phase 0: bilinear meta (row-pair base + eq + folded weights) ----
  const float* ob0 = op0 + (size_t)b * 18 * HW + (size_t)ho * Ww;
  const float* ob1 = op1 + (size_t)b * 18 * HW + (size_t)ho * Ww;
  for (int i = tid; i < NKK * 64; i += 512) {
    int pp = i & 63;
    int kk = i >> 6;
    int ky = kk / 3, kx = kk % 3;
    float dy = ob0[(size_t)(2 * kk) * HW + pp] + ob1[(size_t)(2 * kk) * HW + pp];
    float dx = ob0[(size_t)(2 * kk + 1) * HW + pp] + ob1[(size_t)(2 * kk + 1) * HW + pp];
    float py = (float)(ho - 1 + ky) + dy;
    float pxf = (float)(pp - 1 + kx) + dx;
    float y0f = floorf(py), x0f = floorf(pxf);
    int y0 = (int)y0f, x0 = (int)x0f;
    float wy1 = py - y0f, wy0 = 1.0f - wy1;
    float wx1 = pxf - x0f, wx0 = 1.0f - wx1;
    float vy0 = (y0 >= 0 && y0 < Hh) ? 1.0f : 0.0f;
    float vy1 = (y0 + 1 >= 0 && y0 + 1 < Hh) ? 1.0f : 0.0f;
    float vx0 = (x0 >= 0 && x0 < Ww) ? 1.0f : 0.0f;
    float vx1 = (x0 + 1 >= 0 && x0 + 1 < Ww) ? 1.0f : 0.0f;
    int y0c = min(max(y0, 0), Hh - 1);
    int y1c = min(max(y0 + 1, 0), Hh - 1);
    int x0c = min(max(x0, 0), Ww - 2);   // pair [x0c, x0c+1] always in-row
    int eq = (x0 == x0c) ? 1 : 0;
    sm_m[kk][pp] = make_int4(y0c * Ww + x0c, y1c * Ww + x0c, eq, 0);
    sm_w[kk][pp] = make_float4(wy0 * wx0 * vy0 * vx0, wy0 * wx1 * vy0 * vx1,
                               wy1 * wx0 * vy1 * vx0, wy1 * wx1 * vy1 * vx1);
  }
  __syncthreads();

  f32x4 acc[4][2];
  #pragma unroll
  for (int m = 0; m < 4; ++m)
    #pragma unroll
    for (int n = 0; n < 2; ++n)
      #pragma unroll
      for (int q = 0; q < 4; ++q) acc[m][n][q] = 0.0f;

  const float* xb = x + (size_t)b * CIN * HW;
  const int spx = tid & 63;   // stage pixel
  const int sc8 = tid >> 6;   // stage 8-channel group (0..7)
  const int sboff = spx * 128 + ((sc8 ^ (spx & 7)) * 16);

  // ---- prologue: stage chunk 0 (kk=0, cb=0), C loads ----
  {
    int4 ip = sm_m[0][spx];
    float4 wp = sm_w[0][spx];
    const float* xpB = xb + (size_t)(sc8 * 8) * HW;
    unsigned int ph[4], pl[4];
    #pragma unroll
    for (int j2 = 0; j2 < 4; ++j2) {
      const float* xq0 = xpB + (size_t)(2 * j2) * HW;
      const float* xq1 = xpB + (size_t)(2 * j2 + 1) * HW;
      float2 a0 = make_float2(xq0[ip.x], xq0[ip.x + 1]);
      float2 a1 = make_float2(xq0[ip.y], xq0[ip.y + 1]);
      float2 b0 = make_float2(xq1[ip.x], xq1[ip.x + 1]);
      float2 b1 = make_float2(xq1[ip.y], xq1[ip.y + 1]);
      float v0 = bil(a0, a1, ip.z, wp);
      float v1 = bil(b0, b1, ip.z, wp);
      unsigned short h0 = f2bf(v0), h1 = f2bf(v1);
      ph[j2] = (unsigned int)h0 | ((unsigned int)h1 << 16);
      pl[j2] = (unsigned int)f2bf(v0 - bf2f(h0)) | ((unsigned int)f2bf(v1 - bf2f(h1)) << 16);
    }
    *(uint4*)((char*)smAh[0] + sboff) = make_uint4(ph[0], ph[1], ph[2], ph[3]);
    *(uint4*)((char*)smAl[0] + sboff) = make_uint4(pl[0], pl[1], pl[2], pl[3]);
  }
  __syncthreads();

  for (int ch = 0; ch < 36; ++ch) {
    const int cur = ch & 1;
    const int kk = ch >> 2, cb = ch & 3;
    const bool have_next = (ch + 1 < 36);

    // ---- 1. ds_read A-frags: all 4 px-tiles (lgkm counter) ----
    bf16x8 ah[4][2], al[4][2];
    #pragma unroll
    for (int m = 0; m < 4; ++m)
      #pragma unroll
      for (int ks = 0; ks < 2; ++ks) {
        int pxa = m * 16 + (lane & 15);
        int cg = ks * 4 + (lane >> 4);
        int aoff = pxa * 128 + ((cg ^ (pxa & 7)) * 16);
        ah[m][ks] = *(const bf16x8*)((const char*)smAh[cur] + aoff);
        al[m][ks] = *(const bf16x8*)((const char*)smAl[cur] + aoff);
      }

    // ---- 2. asm: 8 weight dwordx4 loads, unique per wave (oldest) ----
    bf16x8 wh[2][2], wl[2][2];
    #pragma unroll
    for (int nt = 0; nt < 2; ++nt)
      #pragma unroll
      for (int ks = 0; ks < 2; ++ks) {
        size_t wi = ((((size_t)(kk * 4 + cb) * 16 + (wvu * 2 + nt)) * 2 + ks) * 64 + lane) * 8;
        wh[nt][ks] = gldx4(wBh + wi);
        wl[nt][ks] = gldx4(wBl + wi);
      }

    // ---- 3. asm: 16 pair-gather dwordx2 for chunk ch+1 (young) ----
    float2 g0[8], g1[8];
    int4 ipn; float4 wpn;
    if (have_next) {
      int kkn = (ch + 1) >> 2, cbn = (ch + 1) & 3;
      ipn = sm_m[kkn][spx];
      wpn = sm_w[kkn][spx];
      const float* xpB = xb + (size_t)(cbn * 64 + sc8 * 8) * HW;
      #pragma unroll
      for (int j = 0; j < 8; ++j) {
        const float* xp = xpB + (size_t)j * HW;
        g0[j] = gldx2(xp + ipn.x);
        g1[j] = gldx2(xp + ipn.y);
      }
    }

    // ---- 4. wait weights only (16 gathers stay in flight) ----
    if (have_next) { asm volatile("s_waitcnt vmcnt(16)" ::: "memory"); }
    else           { asm volatile("s_waitcnt vmcnt(0)"  ::: "memory"); }
    __builtin_amdgcn_sched_barrier(0);

    // ---- 5. 48 MFMAs ----
    #pragma unroll
    for (int m = 0; m < 4; ++m)
      #pragma unroll
      for (int nt = 0; nt < 2; ++nt)
        #pragma unroll
        for (int ks = 0; ks < 2; ++ks) {
          acc[m][nt] = __builtin_amdgcn_mfma_f32_16x16x32_bf16(ah[m][ks], wh[nt][ks], acc[m][nt], 0, 0, 0);
          acc[m][nt] = __builtin_amdgcn_mfma_f32_16x16x32_bf16(al[m][ks], wh[nt][ks], acc[m][nt], 0, 0, 0);
          acc[m][nt] = __builtin_amdgcn_mfma_f32_16x16x32_bf16(ah[m][ks], wl[nt][ks], acc[m][nt], 0, 0, 0);
        }

    // ---- 6. drain gathers, staging math, ds_write ----
    if (have_next) {
      asm volatile("s_waitcnt vmcnt(0)" ::: "memory");
      __builtin_amdgcn_sched_barrier(0);
      unsigned int ph[4], pl[4];
      #pragma unroll
      for (int j2 = 0; j2 < 4; ++j2) {
        float v0 = bil(g0[2 * j2], g1[2 * j2], ipn.z, wpn);
        float v1 = bil(g0[2 * j2 + 1], g1[2 * j2 + 1], ipn.z, wpn);
        unsigned short h0 = f2bf(v0), h1 = f2bf(v1);
        ph[j2] = (unsigned int)h0 | ((unsigned int)h1 << 16);
        pl[j2] = (unsigned int)f2bf(v0 - bf2f(h0)) | ((unsigned int)f2bf(v1 - bf2f(h1)) << 16);
      }
      *(uint4*)((char*)smAh[cur ^ 1] + sboff) = make_uint4(ph[0], ph[1], ph[2], ph[3]);
      *(uint4*)((char*)smAl[cur ^ 1] + sboff) = make_uint4(pl[0], pl[1], pl[2], pl[3]);
    }
    __syncthreads();
  }

  // ---- epilogue: wave wvu owns oc 32*wvu..32*wvu+31 over all 64 px ----
  #pragma unroll
  for (int m = 0; m < 4; ++m) {
    #pragma unroll
    for (int nt = 0; nt < 2; ++nt) {
      int oc = wvu * 32 + nt * 16 + (lane & 15);
      int pxo = m * 16 + (lane >> 4) * 4;
      float4 v4 = make_float4(acc[m][nt][0], acc[m][nt][1], acc[m][nt][2], acc[m][nt][3]);
      *(float4*)(out + ((size_t)b * COUT + oc) * HW + (size_t)ho * Ww + pxo) = v4;
    }
  }
}

// ---------------------------------------------------------------------------
extern "C" void kernel_launch(void* const* d_in, const int* in_sizes, int n_in,
                              void* d_out, int out_size, void* d_ws, size_t ws_size,
                              hipStream_t stream) {
  const float* x  = (const float*)d_in[0];
  const float* ow = (const float*)d_in[1];
  const float* ob = (const float*)d_in[2];
  const float* w  = (const float*)d_in[3];
  float* out = (float*)d_out;

  float* op0 = (float*)d_ws;
  float* op1 = op0 + OFFPART_FLOATS;
  unsigned short* wBh  = (unsigned short*)(op1 + OFFPART_FLOATS);
  unsigned short* wBl  = wBh + WB_ELEMS;
  unsigned short* wOBh = wBl + WB_ELEMS;

  hipLaunchKernelGGL(prep_weights_kernel, dim3((WB_ELEMS + WOB_ELEMS) / 256),
                     dim3(256), 0, stream, w, ow, wBh, wBl, wOBh);
  hipLaunchKernelGGL(offset_conv_kernel, dim3(Bb * Hh * 2), dim3(256),
                     0, stream, x, wOBh, ob, op0, op1);
  hipLaunchKernelGGL(deform_main_kernel, dim3(Bb * Hh), dim3(512),
                     0, stream, x, op0, op1, wBh, wBl, out);
}